// Round 3
// baseline (494.712 us; speedup 1.0000x reference)
//
#include <hip/hip_runtime.h>
#include <stdint.h>

typedef unsigned short u16;
typedef unsigned int u32;
typedef __bf16 bf16x8 __attribute__((ext_vector_type(8)));
typedef float f32x4 __attribute__((ext_vector_type(4)));

#define SEQ 2048
#define BZ 16
#define DIM 1024

__device__ __forceinline__ u16 f2bf(float f) {
    union { float f; u32 u; } a; a.f = f;
    u32 r = a.u + 0x7FFFu + ((a.u >> 16) & 1u);   // RNE
    return (u16)(r >> 16);
}
__device__ __forceinline__ void async16(const u16* g, u16* l) {
    __builtin_amdgcn_global_load_lds(
        (const __attribute__((address_space(1))) void*)g,
        (__attribute__((address_space(3))) void*)l, 16, 0, 0);
}

// ---------------------------------------------------------------------------
// prep: fused (all parts independent, branch on blockIdx)
//   u in [0,2048):        xb[b][s][d] = bf16(x[s][b][d])            (slab s=u)
//   u in [2048,19456):    Wbt[z][f][e]=W[id_z][e][f]; Wt[d][e]=W_base[e][d]
//   u in [19456,19520):   bb[b][f] = sum_e b_base[e]*W[id_b][e][f] + bias[id_b][f]
// ---------------------------------------------------------------------------
__global__ void prep_kernel(const float* __restrict__ x,
                            const float* __restrict__ W,
                            const float* __restrict__ W_base,
                            const float* __restrict__ b_base,
                            const float* __restrict__ bias,
                            const int* __restrict__ lang_ids,
                            const int* __restrict__ dict_len,
                            u16* __restrict__ xb,
                            u16* __restrict__ Wt,
                            u16* __restrict__ Wbt,
                            float* __restrict__ bb)
{
    __shared__ float tile[32][33];
    int u = blockIdx.x;
    int tid = threadIdx.x;

    if (u < 2048) {
        // ---- x convert + transpose (s<->b) ----
        int s = u;
        const float4* src = (const float4*)(x + (size_t)s * BZ * DIM);
        #pragma unroll
        for (int j = 0; j < 16; j++) {
            int idx = j * 256 + tid;            // float4 index in [0, 4096)
            float4 v = src[idx];
            int e = idx * 4;
            int b = e >> 10, d = e & 1023;
            u32 lo = f2bf(v.x) | ((u32)f2bf(v.y) << 16);
            u32 hi = f2bf(v.z) | ((u32)f2bf(v.w) << 16);
            *(uint2*)(xb + ((size_t)b * SEQ + s) * DIM + d) = make_uint2(lo, hi);
        }
    } else if (u < 19456) {
        // ---- weight transpose + convert ----
        int t = u - 2048;                       // 0..17407
        int z = t >> 10;                        // 0..16
        int w = t & 1023;
        int x0 = (w & 31) * 32, y0 = (w >> 5) * 32;
        const float* S;
        u16* D;
        if (z < BZ) {
            int id = dict_len[0] - 1 - lang_ids[z];
            S = W + (size_t)id * DIM * DIM;
            D = Wbt + (size_t)z * DIM * DIM;
        } else {
            S = W_base;
            D = Wt;
        }
        int tx = tid & 31, ty = tid >> 5;       // 32 x 8
        #pragma unroll
        for (int i = 0; i < 4; i++)
            tile[ty + 8 * i][tx] = S[(size_t)(y0 + ty + 8 * i) * DIM + x0 + tx];
        __syncthreads();
        #pragma unroll
        for (int i = 0; i < 4; i++)
            D[(size_t)(x0 + ty + 8 * i) * DIM + y0 + tx] = f2bf(tile[tx][ty + 8 * i]);
    } else {
        // ---- bb (fp32, straight from W) ----
        int v = u - 19456;                      // 0..63
        int b = v >> 2;
        int f = (v & 3) * 256 + tid;
        int id = dict_len[0] - 1 - lang_ids[b];
        const float* Wp = W + (size_t)id * DIM * DIM + f;
        float acc = 0.f;
        #pragma unroll 4
        for (int e = 0; e < DIM; e++)
            acc += b_base[e] * Wp[(size_t)e * DIM];
        bb[b * DIM + f] = acc + bias[(size_t)id * DIM + f];
    }
}

// ---------------------------------------------------------------------------
// gemm1: CT[b][f][d] = sum_e Wbt[b][f][e] * Wt[d][e]   (bf16 out)
// 1D grid 1024, XCD-affinity swizzle on b; LDS xor-swizzle
// ---------------------------------------------------------------------------
__global__ void gemm1_kernel(const u16* __restrict__ Wbt,
                             const u16* __restrict__ Wt,
                             u16* __restrict__ CT)
{
    int id0 = blockIdx.x;
    int xcd = id0 & 7;
    int i = id0 >> 3;                 // 0..127
    int b = xcd + 8 * (i >> 6);
    int j = i & 63;
    int d0 = (j & 7) * 128;
    int f0 = (j >> 3) * 128;

    const u16* A = Wbt + (size_t)b * DIM * DIM;   // [f][e]
    const u16* B = Wt;                            // [d][e]
    u16* C = CT + (size_t)b * DIM * DIM;          // [f][d]

    __shared__ u16 As[128 * 32];
    __shared__ u16 Bs[128 * 32];

    int tid = threadIdx.x;
    int wave = tid >> 6, lane = tid & 63;
    int wm = (wave >> 1) * 64, wn = (wave & 1) * 64;
    int quad = lane >> 4, lr = lane & 15;
    int sq = (quad ^ (lr & 3)) * 8;   // xor-swizzled fragment column

    // staging: lane l covers row (l>>2), swizzled col 8*((l&3)^((l>>2)&3))
    int srow = wave * 32 + (lane >> 2);
    int scol = 8 * ((lane & 3) ^ ((lane >> 2) & 3));
    const u16* ga0 = A + (size_t)(f0 + srow) * DIM + scol;
    const u16* ga1 = ga0 + (size_t)16 * DIM;
    const u16* gb0 = B + (size_t)(d0 + srow) * DIM + scol;
    const u16* gb1 = gb0 + (size_t)16 * DIM;
    u16* la0 = &As[(wave * 32) * 32];
    u16* la1 = &As[(wave * 32 + 16) * 32];
    u16* lb0 = &Bs[(wave * 32) * 32];
    u16* lb1 = &Bs[(wave * 32 + 16) * 32];

    f32x4 acc[4][4];
    #pragma unroll
    for (int mi = 0; mi < 4; mi++)
        #pragma unroll
        for (int nj = 0; nj < 4; nj++)
            #pragma unroll
            for (int e = 0; e < 4; e++) acc[mi][nj][e] = 0.f;

    for (int k0 = 0; k0 < DIM; k0 += 32) {
        async16(ga0, la0); async16(ga1, la1);
        async16(gb0, lb0); async16(gb1, lb1);
        ga0 += 32; ga1 += 32; gb0 += 32; gb1 += 32;
        __syncthreads();
        bf16x8 af[4], bfv[4];
        #pragma unroll
        for (int mt = 0; mt < 4; mt++)
            af[mt] = *(const bf16x8*)&As[(wm + mt * 16 + lr) * 32 + sq];
        #pragma unroll
        for (int nt = 0; nt < 4; nt++)
            bfv[nt] = *(const bf16x8*)&Bs[(wn + nt * 16 + lr) * 32 + sq];
        #pragma unroll
        for (int mt = 0; mt < 4; mt++)
            #pragma unroll
            for (int nt = 0; nt < 4; nt++)
                acc[mt][nt] = __builtin_amdgcn_mfma_f32_16x16x32_bf16(
                    af[mt], bfv[nt], acc[mt][nt], 0, 0, 0);
        __syncthreads();
    }
    #pragma unroll
    for (int mt = 0; mt < 4; mt++) {
        int fr = f0 + wm + mt * 16 + quad * 4;
        #pragma unroll
        for (int nt = 0; nt < 4; nt++) {
            int dc = d0 + wn + nt * 16 + lr;
            #pragma unroll
            for (int rr = 0; rr < 4; rr++)
                C[(size_t)(fr + rr) * DIM + dc] = f2bf(acc[mt][nt][rr]);
        }
    }
}

// ---------------------------------------------------------------------------
// gemm2: out[s][b][f] = sum_d xb[b][s][d] * CT[b][f][d] + bb[b][f]
// 1D grid 2048, XCD-affinity swizzle on b; LDS xor-swizzle
// ---------------------------------------------------------------------------
__global__ void gemm2_kernel(const u16* __restrict__ xb,
                             const u16* __restrict__ CT,
                             const float* __restrict__ bb,
                             float* __restrict__ out)
{
    int id0 = blockIdx.x;
    int xcd = id0 & 7;
    int i = id0 >> 3;                 // 0..255
    int b = xcd + 8 * (i >> 7);
    int j = i & 127;
    int f0 = (j & 7) * 128;
    int s0 = (j >> 3) * 128;

    const u16* A = xb + (size_t)b * SEQ * DIM;    // [s][d]
    const u16* Bm = CT + (size_t)b * DIM * DIM;   // [f][d]

    __shared__ u16 As[128 * 32];
    __shared__ u16 Bs[128 * 32];

    int tid = threadIdx.x;
    int wave = tid >> 6, lane = tid & 63;
    int wm = (wave >> 1) * 64, wn = (wave & 1) * 64;
    int quad = lane >> 4, lr = lane & 15;
    int sq = (quad ^ (lr & 3)) * 8;

    int srow = wave * 32 + (lane >> 2);
    int scol = 8 * ((lane & 3) ^ ((lane >> 2) & 3));
    const u16* ga0 = A + (size_t)(s0 + srow) * DIM + scol;
    const u16* ga1 = ga0 + (size_t)16 * DIM;
    const u16* gb0 = Bm + (size_t)(f0 + srow) * DIM + scol;
    const u16* gb1 = gb0 + (size_t)16 * DIM;
    u16* la0 = &As[(wave * 32) * 32];
    u16* la1 = &As[(wave * 32 + 16) * 32];
    u16* lb0 = &Bs[(wave * 32) * 32];
    u16* lb1 = &Bs[(wave * 32 + 16) * 32];

    f32x4 acc[4][4];
    #pragma unroll
    for (int mi = 0; mi < 4; mi++)
        #pragma unroll
        for (int nj = 0; nj < 4; nj++)
            #pragma unroll
            for (int e = 0; e < 4; e++) acc[mi][nj][e] = 0.f;

    for (int k0 = 0; k0 < DIM; k0 += 32) {
        async16(ga0, la0); async16(ga1, la1);
        async16(gb0, lb0); async16(gb1, lb1);
        ga0 += 32; ga1 += 32; gb0 += 32; gb1 += 32;
        __syncthreads();
        bf16x8 af[4], bfv[4];
        #pragma unroll
        for (int mt = 0; mt < 4; mt++)
            af[mt] = *(const bf16x8*)&As[(wm + mt * 16 + lr) * 32 + sq];
        #pragma unroll
        for (int nt = 0; nt < 4; nt++)
            bfv[nt] = *(const bf16x8*)&Bs[(wn + nt * 16 + lr) * 32 + sq];
        #pragma unroll
        for (int mt = 0; mt < 4; mt++)
            #pragma unroll
            for (int nt = 0; nt < 4; nt++)
                acc[mt][nt] = __builtin_amdgcn_mfma_f32_16x16x32_bf16(
                    af[mt], bfv[nt], acc[mt][nt], 0, 0, 0);
        __syncthreads();
    }
    #pragma unroll
    for (int nt = 0; nt < 4; nt++) {
        int fcol = f0 + wn + nt * 16 + lr;
        float bv = bb[b * DIM + fcol];
        #pragma unroll
        for (int mt = 0; mt < 4; mt++) {
            int sr = s0 + wm + mt * 16 + quad * 4;
            #pragma unroll
            for (int rr = 0; rr < 4; rr++)
                out[((size_t)(sr + rr) * BZ + b) * DIM + fcol] = acc[mt][nt][rr] + bv;
        }
    }
}

extern "C" void kernel_launch(void* const* d_in, const int* in_sizes, int n_in,
                              void* d_out, int out_size, void* d_ws, size_t ws_size,
                              hipStream_t stream)
{
    const float* x        = (const float*)d_in[0];
    const int*   lang_ids = (const int*)d_in[1];
    const float* W_base   = (const float*)d_in[2];
    const float* b_base   = (const float*)d_in[3];
    const float* W        = (const float*)d_in[4];
    const float* bias     = (const float*)d_in[5];
    const int*   dict_len = (const int*)d_in[6];
    float* out = (float*)d_out;

    char* ws = (char*)d_ws;
    u16*  Wt  = (u16*)ws;                                   // 2 MB
    u16*  Wbt = (u16*)(ws + (size_t)(2u << 20));            // 32 MB
    u16*  CT  = (u16*)(ws + (size_t)(34u << 20));           // 32 MB
    float* bb = (float*)(ws + (size_t)(66u << 20));         // 64 KB
    u16*  xb  = (u16*)(ws + (size_t)(67u << 20));           // 64 MB

    prep_kernel<<<dim3(19520, 1, 1), 256, 0, stream>>>(
        x, W, W_base, b_base, bias, lang_ids, dict_len, xb, Wt, Wbt, bb);
    gemm1_kernel<<<dim3(1024, 1, 1), 256, 0, stream>>>(Wbt, Wt, CT);
    gemm2_kernel<<<dim3(2048, 1, 1), 256, 0, stream>>>(xb, CT, bb, out);
}